// Round 3
// baseline (138.768 us; speedup 1.0000x reference)
//
#include <hip/hip_runtime.h>

#define NV 65536       // total vectors (16*4096)
#define D 64           // embedding dim
#define K 1024         // codebook size
#define BM 256         // vectors per block
#define BK 256         // codes per LDS tile (4 tiles)
#define NT 512         // threads per block (8 waves)
#define RS 264         // row stride in words for xT/eT (16B-aligned, bank-shift 8)
#define LOSS_OFF 4194304
#define IDX_OFF  4194305

// Per-code squared norms, replicating numpy fp32 pairwise-8 summation exactly.
__global__ void vq_prep(const float* __restrict__ E, float* __restrict__ eSq,
                        float* __restrict__ loss) {
  int k = blockIdx.x * 256 + threadIdx.x;
  if (k == 0) *loss = 0.0f;
  if (k < K) {
    const float* row = E + (size_t)k * D;
    float r[8];
#pragma unroll
    for (int j = 0; j < 8; ++j) r[j] = __fmul_rn(row[j], row[j]);
#pragma unroll
    for (int i = 8; i < D; i += 8)
#pragma unroll
      for (int j = 0; j < 8; ++j)
        r[j] = __fadd_rn(r[j], __fmul_rn(row[i + j], row[i + j]));
    eSq[k] = __fadd_rn(
        __fadd_rn(__fadd_rn(r[0], r[1]), __fadd_rn(r[2], r[3])),
        __fadd_rn(__fadd_rn(r[4], r[5]), __fadd_rn(r[6], r[7])));
  }
}

__global__ __launch_bounds__(NT, 2) void vq_main(
    const float* __restrict__ X, const float* __restrict__ E,
    const float* __restrict__ eSq, float* __restrict__ out) {
  __shared__ float xT[D * RS];   // 67584 B, [d][v]
  __shared__ float eT[D * RS];   // 67584 B, [d][swizzled code pos]
  __shared__ float sxx[BM];
  __shared__ int sidx[BM];

  const int t = threadIdx.x;
  const int bv0 = blockIdx.x * BM;
  const int tx = t & 15;   // 16 code groups x 16 codes = 256 codes/tile
  const int ty = t >> 4;   // 32 vec groups x 8 vectors = 256 vectors
  const int v0 = ty * 8;

  // Stage X transposed. Lanes take consecutive v (dc uniform per wave):
  // LDS write bank = (8w+v)%32 with v consecutive -> 2-way (free).
#pragma unroll
  for (int i = 0; i < 8; ++i) {
    int c = t + NT * i;
    int v = c & 255, dc = c >> 8;
    float4 x4 = *reinterpret_cast<const float4*>(X + (size_t)(bv0 + v) * D + dc * 4);
    xT[(dc * 4 + 0) * RS + v] = x4.x;
    xT[(dc * 4 + 1) * RS + v] = x4.y;
    xT[(dc * 4 + 2) * RS + v] = x4.z;
    xT[(dc * 4 + 3) * RS + v] = x4.w;
  }
  // Stage E tile 0, swizzled so compute reads are lane-contiguous:
  // code c = tx*16 + 4j + w lives at pos = j*64 + tx*4 + w.
#pragma unroll
  for (int i = 0; i < 8; ++i) {
    int c = t + NT * i;
    int code = c & 255, dc = c >> 8;
    float4 e4 = *reinterpret_cast<const float4*>(E + (size_t)code * D + dc * 4);
    int pos = ((code >> 2) & 3) * 64 + (code >> 4) * 4 + (code & 3);
    eT[(dc * 4 + 0) * RS + pos] = e4.x;
    eT[(dc * 4 + 1) * RS + pos] = e4.y;
    eT[(dc * 4 + 2) * RS + pos] = e4.z;
    eT[(dc * 4 + 3) * RS + pos] = e4.w;
  }
  __syncthreads();

  // numpy-exact ||x||^2 (pairwise-8, separate mul/add rounding).
  if (t < BM) {
    float r[8];
#pragma unroll
    for (int j = 0; j < 8; ++j) {
      float x0 = xT[j * RS + t];
      r[j] = __fmul_rn(x0, x0);
    }
#pragma unroll
    for (int i = 8; i < D; i += 8)
#pragma unroll
      for (int j = 0; j < 8; ++j) {
        float xi = xT[(i + j) * RS + t];
        r[j] = __fadd_rn(r[j], __fmul_rn(xi, xi));
      }
    sxx[t] = __fadd_rn(
        __fadd_rn(__fadd_rn(r[0], r[1]), __fadd_rn(r[2], r[3])),
        __fadd_rn(__fadd_rn(r[4], r[5]), __fadd_rn(r[6], r[7])));
  }
  __syncthreads();

  float xxv[8];
#pragma unroll
  for (int jv = 0; jv < 8; ++jv) xxv[jv] = sxx[v0 + jv];

  float best[8];
  int bidx[8];
#pragma unroll
  for (int jv = 0; jv < 8; ++jv) { best[jv] = 3.4e38f; bidx[jv] = 0; }

  for (int tile = 0; tile < K / BK; ++tile) {
    float acc[16][8];
#pragma unroll
    for (int cc = 0; cc < 16; ++cc)
#pragma unroll
      for (int jv = 0; jv < 8; ++jv) acc[cc][jv] = 0.0f;

    // 128 FMA per 6 ds_read_b128 -> LDS pipe below VALU floor.
#pragma unroll 2
    for (int d = 0; d < D; ++d) {
      const float* er = eT + d * RS;
      const float* xr = xT + d * RS + v0;
      float4 e0 = *reinterpret_cast<const float4*>(er + tx * 4);
      float4 e1 = *reinterpret_cast<const float4*>(er + 64 + tx * 4);
      float4 e2 = *reinterpret_cast<const float4*>(er + 128 + tx * 4);
      float4 e3 = *reinterpret_cast<const float4*>(er + 192 + tx * 4);
      float4 xa = *reinterpret_cast<const float4*>(xr);
      float4 xb = *reinterpret_cast<const float4*>(xr + 4);
      float ev[16] = {e0.x, e0.y, e0.z, e0.w, e1.x, e1.y, e1.z, e1.w,
                      e2.x, e2.y, e2.z, e2.w, e3.x, e3.y, e3.z, e3.w};
      float xv[8] = {xa.x, xa.y, xa.z, xa.w, xb.x, xb.y, xb.z, xb.w};
#pragma unroll
      for (int cc = 0; cc < 16; ++cc)
#pragma unroll
        for (int jv = 0; jv < 8; ++jv)
          acc[cc][jv] = fmaf(ev[cc], xv[jv], acc[cc][jv]);
    }

    // Reference-exact fp32 score; strict < in ascending code order.
    int cbase = tile * BK + tx * 16;
#pragma unroll
    for (int j = 0; j < 4; ++j) {
      float4 es4 = *reinterpret_cast<const float4*>(eSq + cbase + j * 4);
      float es[4] = {es4.x, es4.y, es4.z, es4.w};
#pragma unroll
      for (int w = 0; w < 4; ++w) {
        int code = cbase + j * 4 + w;
#pragma unroll
        for (int jv = 0; jv < 8; ++jv) {
          float A = __fadd_rn(xxv[jv], es[w]);
          float dq = __fsub_rn(A, 2.0f * acc[4 * j + w][jv]);
          if (dq < best[jv]) { best[jv] = dq; bidx[jv] = code; }
        }
      }
    }

    __syncthreads();  // all eT reads for this tile done
    if (tile < K / BK - 1) {
      int cg = (tile + 1) * BK;
#pragma unroll
      for (int i = 0; i < 8; ++i) {
        int c = t + NT * i;
        int code = c & 255, dc = c >> 8;
        float4 e4 = *reinterpret_cast<const float4*>(
            E + (size_t)(cg + code) * D + dc * 4);
        int pos = ((code >> 2) & 3) * 64 + (code >> 4) * 4 + (code & 3);
        eT[(dc * 4 + 0) * RS + pos] = e4.x;
        eT[(dc * 4 + 1) * RS + pos] = e4.y;
        eT[(dc * 4 + 2) * RS + pos] = e4.z;
        eT[(dc * 4 + 3) * RS + pos] = e4.w;
      }
      __syncthreads();
    }
  }

  // Lexicographic (val, idx) argmin across the 16 tx lanes (in-wave groups).
#pragma unroll
  for (int jv = 0; jv < 8; ++jv) {
    float bv = best[jv];
    int bi = bidx[jv];
#pragma unroll
    for (int off = 1; off < 16; off <<= 1) {
      float ov = __shfl_xor(bv, off, 64);
      int oi = __shfl_xor(bi, off, 64);
      if (ov < bv || (ov == bv && oi < bi)) { bv = ov; bi = oi; }
    }
    if (tx == 0) sidx[v0 + jv] = bi;
  }
  __syncthreads();

  // Epilogue: gather codebook rows, write quantized, accumulate loss.
  float lsum = 0.0f;
#pragma unroll
  for (int i = 0; i < 8; ++i) {
    int c = t + NT * i;
    int v = c >> 4, dc = c & 15;
    int code = sidx[v];
    float4 e4 = *reinterpret_cast<const float4*>(E + (size_t)code * D + dc * 4);
    float x0 = xT[(dc * 4 + 0) * RS + v];
    float x1 = xT[(dc * 4 + 1) * RS + v];
    float x2 = xT[(dc * 4 + 2) * RS + v];
    float x3 = xT[(dc * 4 + 3) * RS + v];
    float d0 = e4.x - x0, d1 = e4.y - x1, d2 = e4.z - x2, d3 = e4.w - x3;
    lsum += d0 * d0 + d1 * d1 + d2 * d2 + d3 * d3;
    *reinterpret_cast<float4*>(out + (size_t)(bv0 + v) * D + dc * 4) = e4;
  }
  if (t < BM) out[IDX_OFF + bv0 + t] = (float)sidx[t];

#pragma unroll
  for (int off = 1; off < 64; off <<= 1) lsum += __shfl_xor(lsum, off, 64);
  if ((t & 63) == 0)
    atomicAdd(out + LOSS_OFF, lsum * (1.25f / (float)((size_t)NV * D)));
}

extern "C" void kernel_launch(void* const* d_in, const int* in_sizes, int n_in,
                              void* d_out, int out_size, void* d_ws, size_t ws_size,
                              hipStream_t stream) {
  const float* X = (const float*)d_in[0];
  const float* E = (const float*)d_in[1];
  float* out = (float*)d_out;
  float* eSq = (float*)d_ws;  // 4 KB scratch
  vq_prep<<<4, 256, 0, stream>>>(E, eSq, out + LOSS_OFF);
  vq_main<<<NV / BM, NT, 0, stream>>>(X, E, eSq, out);
}